// Round 9
// baseline (465.324 us; speedup 1.0000x reference)
//
#include <hip/hip_runtime.h>
#include <math.h>

#define NB 8192     // batch rows
#define DD 512      // hidden dim
#define KC 4096     // codebook size
#define NL 4        // layers

#define NTB 32      // part[] column tiles (128 codes each)
#define MARGIN 4.0f // bf16-dot candidate margin (>> 2*max bf16 dot error ~0.3)

#define GBM 256
#define GBN 256

typedef __bf16 bf16x8 __attribute__((ext_vector_type(8)));
typedef float  f32x4  __attribute__((ext_vector_type(4)));
typedef unsigned short u16;
typedef unsigned int   u32;

struct Top2 { float v1; int i1; float v2; int i2; };

__device__ __forceinline__ u16 f2bf(float f) {   // RNE fp32 -> bf16
    unsigned u = __float_as_uint(f);
    return (u16)((u + 0x7fffu + ((u >> 16) & 1u)) >> 16);
}

__device__ __forceinline__ u32 umaxu(u32 a, u32 b) { return a > b ? a : b; }
__device__ __forceinline__ u32 uminu(u32 a, u32 b) { return a < b ? a : b; }

// monotonic fp32 -> u32 (order-preserving, incl. negatives)
__device__ __forceinline__ u32 packmono(float f) {
    u32 u = __float_as_uint(f);
    return u ^ (((u32)((int)u >> 31)) | 0x80000000u);
}
__device__ __forceinline__ float unpackv(u32 p) {
    u32 q = p & 0xFFFFFF80u;
    u32 u = (q & 0x80000000u) ? (q ^ 0x80000000u) : ~q;
    return __uint_as_float(u);
}

// fp32 -> bf16 bulk convert (n4 = count/4)
__global__ __launch_bounds__(256)
void k_cvt_bf16(const float* __restrict__ src, u16* __restrict__ dst, int n4)
{
    const int i = blockIdx.x * 256 + threadIdx.x;
    if (i < n4) {
        const float4 f = ((const float4*)src)[i];
        uint2 p;
        p.x = (unsigned)f2bf(f.x) | ((unsigned)f2bf(f.y) << 16);
        p.y = (unsigned)f2bf(f.z) | ((unsigned)f2bf(f.w) << 16);
        ((uint2*)dst)[i] = p;
    }
}

// bf16 MFMA GEMM sim = Rb [NB x DD] @ Cb^T [KC x DD], 256x256 tile, BK=32.
// R9: register-double-buffered FRAGMENT prefetch -- per step: issue ds_read of
// tile t+1 frags first, MFMA tile t from regs (covers read latency), ds_write
// tile t+2, issue global loads t+4, one lgkm(0)+s_barrier. Removes the
// barrier->read->MFMA serial path that R8's counters exposed. Staging swizzle
// and branchless packed-u32 top-2 epilogue unchanged from R8.
__global__ __launch_bounds__(512, 2)
void k_simtop2(const u16* __restrict__ Rb, const u16* __restrict__ Cb,
               Top2* __restrict__ part /* [NB][NTB] */)
{
    __shared__ __align__(16) u16 As[2][8192];   // [buf][256 rows x 32 k] = 32 KB
    __shared__ __align__(16) u16 Bs[2][8192];   // 32 KB

    const int tid  = threadIdx.x;
    const int lane = tid & 63;
    const int w    = tid >> 6;        // 0..7
    const int wm   = w >> 2;          // 0..1  (row half)
    const int wn   = w & 3;           // 0..3  (col quarter)

    // XCD chunking: 512 blocks -> 8 chunks of 8x8 tiles (A 2MB + B 2MB ~ L2)
    const int bid = blockIdx.x;
    const int xcd = bid & 7;
    const int idx = bid >> 3;                           // 0..63
    const int row_pan  = (xcd >> 1) * 8 + (idx >> 3);   // 0..31
    const int col_tile = (xcd & 1) * 8 + (idx & 7);     // 0..15
    const int rb0 = row_pan * GBM;
    const int cb0 = col_tile * GBN;

    // staging: thread covers row r = tid>>1, k-chunk pair {2h, 2h+1}, h = tid&1.
    // global chunk c stored at LDS chunk c ^ f(r), f(r) = (r&3)^((r>>2)&3).
    const int rowA = tid >> 1;
    const int h    = tid & 1;
    const int fr   = (rowA & 3) ^ ((rowA >> 2) & 3);
    const char* gAb = (const char*)Rb + (size_t)(rb0 + rowA) * 1024 + h * 32;
    const char* gBb = (const char*)Cb + (size_t)(cb0 + rowA) * 1024 + h * 32;
    const int wpos0 = rowA * 64 + (((2 * h)     ^ fr) << 4);
    const int wpos1 = rowA * 64 + (((2 * h + 1) ^ fr) << 4);

    // fragment reads: row = wsub + m*16 + la, chunk = ks ^ f(la)
    const int la = lane & 15, ks = lane >> 4;
    const int fla = (la & 3) ^ ((la >> 2) & 3);
    const int offA = (wm * 128 + la) * 64 + ((ks ^ fla) << 4);
    const int offB = (wn * 64  + la) * 64 + ((ks ^ fla) << 4);

    f32x4 acc[8][4];
    const f32x4 zero = {0.f, 0.f, 0.f, 0.f};
#pragma unroll
    for (int m = 0; m < 8; ++m)
#pragma unroll
        for (int n = 0; n < 4; ++n) acc[m][n] = zero;

    uint4 eA0, eA1, eB0, eB1;   // even-tile staging regs
    uint4 oA0, oA1, oB0, oB1;   // odd-tile staging regs
    bf16x8 fea[8], feb[4];      // even-tile fragment regs
    bf16x8 foa[8], fob[4];      // odd-tile fragment regs

#define LOADE(T) do { const char* _pa = gAb + (T) * 64;                   \
        eA0 = *(const uint4*)(_pa); eA1 = *(const uint4*)(_pa + 16);      \
        const char* _pb = gBb + (T) * 64;                                 \
        eB0 = *(const uint4*)(_pb); eB1 = *(const uint4*)(_pb + 16); } while (0)
#define LOADO(T) do { const char* _pa = gAb + (T) * 64;                   \
        oA0 = *(const uint4*)(_pa); oA1 = *(const uint4*)(_pa + 16);      \
        const char* _pb = gBb + (T) * 64;                                 \
        oB0 = *(const uint4*)(_pb); oB1 = *(const uint4*)(_pb + 16); } while (0)
#define WRITEE(P) do {                                                    \
        *(uint4*)((char*)&As[P][0] + wpos0) = eA0;                        \
        *(uint4*)((char*)&As[P][0] + wpos1) = eA1;                        \
        *(uint4*)((char*)&Bs[P][0] + wpos0) = eB0;                        \
        *(uint4*)((char*)&Bs[P][0] + wpos1) = eB1; } while (0)
#define WRITEO(P) do {                                                    \
        *(uint4*)((char*)&As[P][0] + wpos0) = oA0;                        \
        *(uint4*)((char*)&As[P][0] + wpos1) = oA1;                        \
        *(uint4*)((char*)&Bs[P][0] + wpos0) = oB0;                        \
        *(uint4*)((char*)&Bs[P][0] + wpos1) = oB1; } while (0)
#define READF(FA, FB, P) do {                                             \
        const char* _rA = (const char*)&As[P][0];                         \
        const char* _rB = (const char*)&Bs[P][0];                         \
        _Pragma("unroll")                                                 \
        for (int m = 0; m < 8; ++m) FA[m] = *(const bf16x8*)(_rA + offA + m * 1024); \
        _Pragma("unroll")                                                 \
        for (int n = 0; n < 4; ++n) FB[n] = *(const bf16x8*)(_rB + offB + n * 1024); } while (0)
#define MFMAS(FA, FB) do {                                                \
        _Pragma("unroll")                                                 \
        for (int m = 0; m < 8; ++m)                                       \
            _Pragma("unroll")                                             \
            for (int n = 0; n < 4; ++n)                                   \
                acc[m][n] = __builtin_amdgcn_mfma_f32_16x16x32_bf16(FA[m], FB[n], acc[m][n], 0, 0, 0); } while (0)
#define DRAINBAR do { asm volatile("s_waitcnt lgkmcnt(0)" ::: "memory");  \
        __builtin_amdgcn_s_barrier(); } while (0)

    // prologue: tiles 0,1 staged + published; tiles 2,3 loads in flight;
    // tile 0 fragments in regs (extra drain+barrier so step 0's WRITEE is safe)
    LOADE(0); LOADO(1);
    WRITEE(0); WRITEO(1);
    LOADE(2); LOADO(3);
    DRAINBAR;
    READF(fea, feb, 0);
    DRAINBAR;

#pragma unroll 1
    for (int k = 0; k < 8; ++k) {
        // even step i=2k: compute tile 2k; prefetch frags of 2k+1
        READF(foa, fob, 1);
        __builtin_amdgcn_sched_barrier(0);
        MFMAS(fea, feb);
        if (k < 7) WRITEE(0);           // tile 2k+2 -> buf0
        if (k < 6) LOADE(2 * k + 4);
        DRAINBAR;
        // odd step i=2k+1: compute tile 2k+1; prefetch frags of 2k+2
        if (k < 7) READF(fea, feb, 0);
        __builtin_amdgcn_sched_barrier(0);
        MFMAS(foa, fob);
        if (k < 7) WRITEO(1);           // tile 2k+3 -> buf1
        if (k < 6) LOADO(2 * k + 5);
        DRAINBAR;
    }
#undef LOADE
#undef LOADO
#undef WRITEE
#undef WRITEO
#undef READF
#undef MFMAS
#undef DRAINBAR

    __syncthreads();                           // LDS free; reuse As for merge
    uint2 (*mrg)[4] = (uint2 (*)[4])&As[0][0]; // [256 rows][4 wave-cols] = 8 KB

    // ---- branchless packed top-2 epilogue (R8, unchanged) ----
    const int rgrp = lane >> 4;
    const int cidx = lane & 15;
    u32 inv[4];
#pragma unroll
    for (int n = 0; n < 4; ++n)
        inv[n] = (u32)(127 - ((wn & 1) * 64 + n * 16 + cidx));

#pragma unroll
    for (int m = 0; m < 8; ++m) {
#pragma unroll
        for (int j = 0; j < 4; ++j) {
            const u32 p0 = (packmono(acc[m][0][j]) & 0xFFFFFF80u) | inv[0];
            const u32 p1 = (packmono(acc[m][1][j]) & 0xFFFFFF80u) | inv[1];
            const u32 p2 = (packmono(acc[m][2][j]) & 0xFFFFFF80u) | inv[2];
            const u32 p3 = (packmono(acc[m][3][j]) & 0xFFFFFF80u) | inv[3];
            const u32 s1 = umaxu(p0, p1), t1 = uminu(p0, p1);
            const u32 s2 = umaxu(p2, p3), t2 = uminu(p2, p3);
            u32 hi = umaxu(s1, s2);
            u32 lo = umaxu(uminu(s1, s2), umaxu(t1, t2));
#pragma unroll
            for (int off = 1; off < 16; off <<= 1) {
                const u32 oh = (u32)__shfl_xor((int)hi, off);
                const u32 ol = (u32)__shfl_xor((int)lo, off);
                const u32 nh = umaxu(hi, oh);
                lo = umaxu(uminu(hi, oh), umaxu(lo, ol));
                hi = nh;
            }
            if (cidx == 0)
                mrg[wm * 128 + m * 16 + rgrp * 4 + j][wn] = make_uint2(hi, lo);
        }
    }
    __syncthreads();
    if (tid < 256) {   // merge wn pairs -> top-2 per 128-code half (same part format)
#pragma unroll
        for (int tau = 0; tau < 2; ++tau) {
            const uint2 a = mrg[tid][tau * 2], b = mrg[tid][tau * 2 + 1];
            const u32 hi = umaxu(a.x, b.x);
            const u32 lo = umaxu(uminu(a.x, b.x), umaxu(a.y, b.y));
            Top2 p;
            p.v1 = unpackv(hi); p.i1 = cb0 + tau * 128 + 127 - (int)(hi & 127u);
            p.v2 = unpackv(lo); p.i2 = cb0 + tau * 128 + 127 - (int)(lo & 127u);
            part[(size_t)(rb0 + tid) * NTB + col_tile * 2 + tau] = p;
        }
    }
}

// Per row: exact fp32 re-dot of candidates within MARGIN of the bf16 max, argmax,
// residual update (fp32 chain via out_stack + bf16 mirror), per-block loss partial
// (no atomics), usage; layer NL-1 also writes quantized = x - r.
__global__ __launch_bounds__(256)
void k_refine(const Top2* __restrict__ part, const float* __restrict__ CB,
              const float* __restrict__ prevBase, size_t prevStride,
              const float* __restrict__ X, float* __restrict__ out_q,
              float* __restrict__ stack, u16* __restrict__ residb,
              float* __restrict__ out_usage, float* __restrict__ pl,
              int layer)
{
    __shared__ float row[DD];
    __shared__ float candV[64];
    __shared__ int   candI[64];
    __shared__ float s_thr;
    __shared__ float wbv[4];
    __shared__ int   wbi[4];
    __shared__ int   s_best;
    __shared__ float red[256];

    const int b = blockIdx.x;
    const int tid = threadIdx.x;
    const float* pr = prevBase + (size_t)b * prevStride;
    row[tid]       = pr[tid];
    row[tid + 256] = pr[tid + 256];
    if (tid < 64) {
        Top2 p = part[(size_t)b * NTB + (tid >> 1)];
        candV[tid] = (tid & 1) ? p.v2 : p.v1;
        candI[tid] = (tid & 1) ? p.i2 : p.i1;
    }
    __syncthreads();
    if (tid < 64) {
        float v = candV[tid];
        for (int off = 1; off < 64; off <<= 1) v = fmaxf(v, __shfl_xor(v, off));
        if (tid == 0) s_thr = v - MARGIN;
    }
    __syncthreads();
    const float thr = s_thr;

    const int wave = tid >> 6;
    const int lane = tid & 63;
    float bestV = -INFINITY;
    int   bestI = 0x7fffffff;
    for (int s = 0; s < 16; ++s) {
        const int c = wave * 16 + s;
        if (candV[c] < thr) continue;          // wave-uniform skip
        const int ci = candI[c];
        const float* cr = CB + (size_t)ci * DD;
        float p = 0.f;
#pragma unroll
        for (int q = 0; q < 8; ++q)
            p = fmaf(row[lane * 8 + q], cr[lane * 8 + q], p);
        for (int off = 32; off >= 1; off >>= 1) p += __shfl_xor(p, off);
        if (p > bestV || (p == bestV && ci < bestI)) { bestV = p; bestI = ci; }
    }
    if (lane == 0) { wbv[wave] = bestV; wbi[wave] = bestI; }
    __syncthreads();
    if (tid == 0) {
        float bv = wbv[0]; int bi = wbi[0];
        for (int k = 1; k < 4; ++k)
            if (wbv[k] > bv || (wbv[k] == bv && wbi[k] < bi)) { bv = wbv[k]; bi = wbi[k]; }
        s_best = bi;
        out_usage[layer * KC + bi] = 1.0f;
    }
    __syncthreads();
    const int bi = s_best;

    const float* cr = CB + (size_t)bi * DD;
    const float rn0 = row[tid]       - cr[tid];
    const float rn1 = row[tid + 256] - cr[tid + 256];
    float* sp = stack + ((size_t)b * NL + layer) * DD;   // base odd-aligned -> scalar
    sp[tid]       = rn0;
    sp[tid + 256] = rn1;
    residb[(size_t)b * DD + tid]       = f2bf(rn0);
    residb[(size_t)b * DD + tid + 256] = f2bf(rn1);
    if (layer == NL - 1) {
        out_q[(size_t)b * DD + tid]       = X[(size_t)b * DD + tid]       - rn0;
        out_q[(size_t)b * DD + tid + 256] = X[(size_t)b * DD + tid + 256] - rn1;
    }
    red[tid] = rn0 * rn0 + rn1 * rn1;
    __syncthreads();
    for (int st = 128; st > 0; st >>= 1) {
        if (tid < st) red[tid] += red[tid + st];
        __syncthreads();
    }
    if (tid == 0) pl[(size_t)layer * NB + b] = red[0];
}

__global__ __launch_bounds__(256)
void k_cbsq(const float* __restrict__ cb, double* __restrict__ cq)
{
    __shared__ double red[256];
    const size_t n = (size_t)NL * KC * DD;
    double s = 0.0;
    for (size_t i = (size_t)blockIdx.x * blockDim.x + threadIdx.x; i < n;
         i += (size_t)gridDim.x * blockDim.x) {
        const float v = cb[i];
        s += (double)v * (double)v;
    }
    red[threadIdx.x] = s;
    __syncthreads();
    for (int st = 128; st > 0; st >>= 1) {
        if (threadIdx.x < st) red[threadIdx.x] += red[threadIdx.x + st];
        __syncthreads();
    }
    if (threadIdx.x == 0) cq[blockIdx.x] = red[0];
}

__global__ __launch_bounds__(256)
void k_finalize(const float* __restrict__ pl, const double* __restrict__ cq,
                float* __restrict__ out_loss)
{
    __shared__ double red[256];
    const int tid = threadIdx.x;
    double s = 0.0;
    for (int i = tid; i < NL * NB; i += 256) s += (double)pl[i];
    double s2 = 0.0;
    for (int i = tid; i < 1024; i += 256) s2 += cq[i];
    red[tid] = s / ((double)NB * DD) + 0.01 * (s2 / ((double)NL * KC));
    __syncthreads();
    for (int st = 128; st > 0; st >>= 1) {
        if (tid < st) red[tid] += red[tid + st];
        __syncthreads();
    }
    if (tid == 0) out_loss[0] = (float)(red[0] / (double)DD);
}

extern "C" void kernel_launch(void* const* d_in, const int* in_sizes, int n_in,
                              void* d_out, int out_size, void* d_ws, size_t ws_size,
                              hipStream_t stream)
{
    (void)in_sizes; (void)n_in; (void)out_size; (void)ws_size;
    const float* x  = (const float*)d_in[0];
    // d_in[1] = temperature: positive scale, argmax-invariant, soft path cancels -> unused
    const float* cb = (const float*)d_in[2];

    float* out       = (float*)d_out;
    float* out_q     = out;                                   // [NB, DD]
    float* out_loss  = out + (size_t)NB * DD;                 // [1]
    float* out_stack = out_loss + 1;                          // [NB, NL, DD] (fp32 residual chain)
    float* out_usage = out_stack + (size_t)NB * NL * DD;      // [NL, KC]

    char* ws = (char*)d_ws;
    Top2*  part   = (Top2*)ws;                                // 4 MB
    u16*   residb = (u16*)(ws + ((size_t)4 << 20));           // 8 MB bf16 residual mirror
    u16*   cbb    = (u16*)(ws + ((size_t)12 << 20));          // 4 MB bf16 codebook (per layer)
    float* pl     = (float*)(ws + ((size_t)16 << 20));        // NL*NB loss partials (128 KB)
    double* cq    = (double*)(ws + ((size_t)16 << 20) + 131072 + 256); // 1024 cbsq partials

    hipMemsetAsync(out_usage, 0, (size_t)NL * KC * sizeof(float), stream);

    k_cvt_bf16<<<(NB * DD / 4 + 255) / 256, 256, 0, stream>>>(x, residb, NB * DD / 4);
    k_cbsq<<<1024, 256, 0, stream>>>(cb, cq);

    for (int l = 0; l < NL; ++l) {
        const float* cbl = cb + (size_t)l * KC * DD;
        k_cvt_bf16<<<(KC * DD / 4 + 255) / 256, 256, 0, stream>>>(cbl, cbb, KC * DD / 4);
        k_simtop2<<<512, 512, 0, stream>>>(residb, cbb, part);
        const float* prevBase = (l == 0) ? x : (out_stack + (size_t)(l - 1) * DD);
        const size_t prevStride = (l == 0) ? (size_t)DD : (size_t)NL * DD;
        k_refine<<<NB, 256, 0, stream>>>(part, cbl, prevBase, prevStride, x, out_q,
                                         out_stack, residb, out_usage, pl, l);
    }
    k_finalize<<<1, 256, 0, stream>>>(pl, cq, out_loss);
}

// Round 10
// 386.458 us; speedup vs baseline: 1.2041x; 1.2041x over previous
//
#include <hip/hip_runtime.h>
#include <math.h>

#define NB 8192     // batch rows
#define DD 512      // hidden dim
#define KC 4096     // codebook size
#define NL 4        // layers

#define NTB 32      // part[] column tiles (128 codes each)
#define MARGIN 4.0f // bf16-dot candidate margin (>> 2*max bf16 dot error ~0.3)

#define GBM 256
#define GBN 256

typedef __bf16 bf16x8 __attribute__((ext_vector_type(8)));
typedef float  f32x4  __attribute__((ext_vector_type(4)));
typedef unsigned short u16;
typedef unsigned int   u32;

struct Top2 { float v1; int i1; float v2; int i2; };

__device__ __forceinline__ u16 f2bf(float f) {   // RNE fp32 -> bf16
    unsigned u = __float_as_uint(f);
    return (u16)((u + 0x7fffu + ((u >> 16) & 1u)) >> 16);
}

__device__ __forceinline__ u32 umaxu(u32 a, u32 b) { return a > b ? a : b; }
__device__ __forceinline__ u32 uminu(u32 a, u32 b) { return a < b ? a : b; }

// monotonic fp32 -> u32 (order-preserving, incl. negatives)
__device__ __forceinline__ u32 packmono(float f) {
    u32 u = __float_as_uint(f);
    return u ^ (((u32)((int)u >> 31)) | 0x80000000u);
}
__device__ __forceinline__ float unpackv(u32 p) {
    u32 q = p & 0xFFFFFF80u;
    u32 u = (q & 0x80000000u) ? (q ^ 0x80000000u) : ~q;
    return __uint_as_float(u);
}

// fp32 -> bf16 bulk convert (n4 = count/4)
__global__ __launch_bounds__(256)
void k_cvt_bf16(const float* __restrict__ src, u16* __restrict__ dst, int n4)
{
    const int i = blockIdx.x * 256 + threadIdx.x;
    if (i < n4) {
        const float4 f = ((const float4*)src)[i];
        uint2 p;
        p.x = (unsigned)f2bf(f.x) | ((unsigned)f2bf(f.y) << 16);
        p.y = (unsigned)f2bf(f.z) | ((unsigned)f2bf(f.w) << 16);
        ((uint2*)dst)[i] = p;
    }
}

// Fused: convert ALL layers' codebooks fp32->bf16 AND accumulate sum(cb^2)
// partials. grid 8192 x 256, one float4 per thread (n4 = NL*KC*DD/4 exactly).
__global__ __launch_bounds__(256)
void k_cvt_cbsq(const float* __restrict__ src, u16* __restrict__ dst,
                double* __restrict__ cq)
{
    __shared__ double red[256];
    const int i = blockIdx.x * 256 + threadIdx.x;
    const float4 f = ((const float4*)src)[i];
    uint2 p;
    p.x = (unsigned)f2bf(f.x) | ((unsigned)f2bf(f.y) << 16);
    p.y = (unsigned)f2bf(f.z) | ((unsigned)f2bf(f.w) << 16);
    ((uint2*)dst)[i] = p;
    red[threadIdx.x] = (double)f.x * f.x + (double)f.y * f.y
                     + (double)f.z * f.z + (double)f.w * f.w;
    __syncthreads();
    for (int st = 128; st > 0; st >>= 1) {
        if (threadIdx.x < st) red[threadIdx.x] += red[threadIdx.x + st];
        __syncthreads();
    }
    if (threadIdx.x == 0) cq[blockIdx.x] = red[0];
}

// bf16 MFMA GEMM sim = Rb [NB x DD] @ Cb^T [KC x DD], 256x256 tile, BK=32.
// R10: same R8 K-loop (register-staged 2 tiles ahead, single s_barrier/tile,
// both-side XOR swizzle, branchless packed top-2 epilogue) but 16 WAVES x 1024
// THREADS: per-wave output 128x32 -> acc 64 f32, frags 40 VGPR, staging 4 uint4.
// Halves per-wave registers so 2 blocks = 32 waves/CU stay resident (R8 sat at
// ~6.4 waves -> latency-bound, all pipes <25%).
__global__ __launch_bounds__(1024, 4)
void k_simtop2(const u16* __restrict__ Rb, const u16* __restrict__ Cb,
               Top2* __restrict__ part /* [NB][NTB] */)
{
    __shared__ __align__(16) u16 As[2][8192];   // [buf][256 rows x 32 k] = 32 KB
    __shared__ __align__(16) u16 Bs[2][8192];   // 32 KB

    const int tid  = threadIdx.x;
    const int lane = tid & 63;
    const int w    = tid >> 6;        // 0..15
    const int wm   = w >> 3;          // 0..1  (row half, 128 rows)
    const int wn   = w & 7;           // 0..7  (32-col slice)

    // XCD chunking: 512 blocks -> 8 chunks of 8x8 tiles (A 2MB + B 2MB ~ L2)
    const int bid = blockIdx.x;
    const int xcd = bid & 7;
    const int idx = bid >> 3;                           // 0..63
    const int row_pan  = (xcd >> 1) * 8 + (idx >> 3);   // 0..31
    const int col_tile = (xcd & 1) * 8 + (idx & 7);     // 0..15
    const int rb0 = row_pan * GBM;
    const int cb0 = col_tile * GBN;

    // staging: thread covers one 16B slot of A and one of B.
    // LDS slot s of row r holds global chunk s ^ f(r), f(r)=(r&3)^((r>>2)&3).
    const int sr  = tid >> 2;          // 0..255
    const int sc  = tid & 3;           // LDS slot
    const int fsr = (sr & 3) ^ ((sr >> 2) & 3);
    const char* gAb = (const char*)Rb + (size_t)(rb0 + sr) * 1024 + ((sc ^ fsr) << 4);
    const char* gBb = (const char*)Cb + (size_t)(cb0 + sr) * 1024 + ((sc ^ fsr) << 4);
    const int wpos = sr * 64 + (sc << 4);

    // fragment reads: row = base + m*16 + la, chunk = ks ^ f(la)
    const int la = lane & 15, ks = lane >> 4;
    const int fla = (la & 3) ^ ((la >> 2) & 3);
    const int offA = (wm * 128 + la) * 64 + ((ks ^ fla) << 4);
    const int offB = (wn * 32  + la) * 64 + ((ks ^ fla) << 4);

    f32x4 acc[8][2];
    const f32x4 zero = {0.f, 0.f, 0.f, 0.f};
#pragma unroll
    for (int m = 0; m < 8; ++m)
#pragma unroll
        for (int n = 0; n < 2; ++n) acc[m][n] = zero;

    uint4 eA, eB, oA, oB;   // staging regs (2 tiles in flight)

#define LOADE(T) do { eA = *(const uint4*)(gAb + (T) * 64);               \
                      eB = *(const uint4*)(gBb + (T) * 64); } while (0)
#define LOADO(T) do { oA = *(const uint4*)(gAb + (T) * 64);               \
                      oB = *(const uint4*)(gBb + (T) * 64); } while (0)

#define ITER(T, rA, rB, P) do {                                           \
        *(uint4*)((char*)&As[P][0] + wpos) = rA;                          \
        *(uint4*)((char*)&Bs[P][0] + wpos) = rB;                          \
        if ((T) + 2 < 16) { if ((T) & 1) LOADO((T) + 2); else LOADE((T) + 2); } \
        asm volatile("s_waitcnt lgkmcnt(0)" ::: "memory");                \
        __builtin_amdgcn_s_barrier();                                     \
        const char* _rA = (const char*)&As[P][0];                         \
        const char* _rB = (const char*)&Bs[P][0];                         \
        bf16x8 av[8], bv[2];                                              \
        _Pragma("unroll")                                                 \
        for (int m = 0; m < 8; ++m) av[m] = *(const bf16x8*)(_rA + offA + m * 1024); \
        _Pragma("unroll")                                                 \
        for (int n = 0; n < 2; ++n) bv[n] = *(const bf16x8*)(_rB + offB + n * 1024); \
        _Pragma("unroll")                                                 \
        for (int m = 0; m < 8; ++m)                                       \
            _Pragma("unroll")                                             \
            for (int n = 0; n < 2; ++n)                                   \
                acc[m][n] = __builtin_amdgcn_mfma_f32_16x16x32_bf16(av[m], bv[n], acc[m][n], 0, 0, 0); \
    } while (0)

    LOADE(0);
    LOADO(1);

#pragma unroll 1
    for (int tt = 0; tt < 16; tt += 2) {
        ITER(tt,     eA, eB, 0);
        ITER(tt + 1, oA, oB, 1);
    }
#undef ITER
#undef LOADE
#undef LOADO

    __syncthreads();                           // LDS free; reuse As for merge
    uint2 (*mrg)[8] = (uint2 (*)[8])&As[0][0]; // [256 rows][8 wave-cols] = 16 KB

    // ---- branchless packed top-2 epilogue ----
    // C row = (lane>>4)*4 + j (batch), col = lane&15 (code).
    // col within 128-half = (wn&3)*32 + n*16 + cidx; key low7 = 127 - that.
    const int rgrp = lane >> 4;
    const int cidx = lane & 15;
    u32 inv[2];
#pragma unroll
    for (int n = 0; n < 2; ++n)
        inv[n] = (u32)(127 - ((wn & 3) * 32 + n * 16 + cidx));

#pragma unroll
    for (int m = 0; m < 8; ++m) {
#pragma unroll
        for (int j = 0; j < 4; ++j) {
            const u32 p0 = (packmono(acc[m][0][j]) & 0xFFFFFF80u) | inv[0];
            const u32 p1 = (packmono(acc[m][1][j]) & 0xFFFFFF80u) | inv[1];
            u32 hi = umaxu(p0, p1);
            u32 lo = uminu(p0, p1);
#pragma unroll
            for (int off = 1; off < 16; off <<= 1) {
                const u32 oh = (u32)__shfl_xor((int)hi, off);
                const u32 ol = (u32)__shfl_xor((int)lo, off);
                const u32 nh = umaxu(hi, oh);
                lo = umaxu(uminu(hi, oh), umaxu(lo, ol));
                hi = nh;
            }
            if (cidx == 0)
                mrg[wm * 128 + m * 16 + rgrp * 4 + j][wn] = make_uint2(hi, lo);
        }
    }
    __syncthreads();
    if (tid < 512) {   // merge 4 wn slices -> top-2 per 128-code half
        const int row = tid & 255, tau = tid >> 8;
        const uint2 a = mrg[row][tau * 4 + 0], b = mrg[row][tau * 4 + 1];
        const uint2 c = mrg[row][tau * 4 + 2], d = mrg[row][tau * 4 + 3];
        const u32 h0 = umaxu(a.x, b.x);
        const u32 l0 = umaxu(uminu(a.x, b.x), umaxu(a.y, b.y));
        const u32 h1 = umaxu(c.x, d.x);
        const u32 l1 = umaxu(uminu(c.x, d.x), umaxu(c.y, d.y));
        const u32 hi = umaxu(h0, h1);
        const u32 lo = umaxu(uminu(h0, h1), umaxu(l0, l1));
        Top2 p;
        p.v1 = unpackv(hi); p.i1 = cb0 + tau * 128 + 127 - (int)(hi & 127u);
        p.v2 = unpackv(lo); p.i2 = cb0 + tau * 128 + 127 - (int)(lo & 127u);
        part[(size_t)(rb0 + row) * NTB + col_tile * 2 + tau] = p;
    }
}

// Per row: exact fp32 re-dot of candidates within MARGIN of the bf16 max, argmax,
// residual update (fp32 chain via out_stack + bf16 mirror), per-block loss partial
// (no atomics), usage; layer NL-1 also writes quantized = x - r.
__global__ __launch_bounds__(256)
void k_refine(const Top2* __restrict__ part, const float* __restrict__ CB,
              const float* __restrict__ prevBase, size_t prevStride,
              const float* __restrict__ X, float* __restrict__ out_q,
              float* __restrict__ stack, u16* __restrict__ residb,
              float* __restrict__ out_usage, float* __restrict__ pl,
              int layer)
{
    __shared__ float row[DD];
    __shared__ float candV[64];
    __shared__ int   candI[64];
    __shared__ float s_thr;
    __shared__ float wbv[4];
    __shared__ int   wbi[4];
    __shared__ int   s_best;
    __shared__ float red[256];

    const int b = blockIdx.x;
    const int tid = threadIdx.x;
    const float* pr = prevBase + (size_t)b * prevStride;
    row[tid]       = pr[tid];
    row[tid + 256] = pr[tid + 256];
    if (tid < 64) {
        Top2 p = part[(size_t)b * NTB + (tid >> 1)];
        candV[tid] = (tid & 1) ? p.v2 : p.v1;
        candI[tid] = (tid & 1) ? p.i2 : p.i1;
    }
    __syncthreads();
    if (tid < 64) {
        float v = candV[tid];
        for (int off = 1; off < 64; off <<= 1) v = fmaxf(v, __shfl_xor(v, off));
        if (tid == 0) s_thr = v - MARGIN;
    }
    __syncthreads();
    const float thr = s_thr;

    const int wave = tid >> 6;
    const int lane = tid & 63;
    float bestV = -INFINITY;
    int   bestI = 0x7fffffff;
    for (int s = 0; s < 16; ++s) {
        const int c = wave * 16 + s;
        if (candV[c] < thr) continue;          // wave-uniform skip
        const int ci = candI[c];
        const float* cr = CB + (size_t)ci * DD;
        float p = 0.f;
#pragma unroll
        for (int q = 0; q < 8; ++q)
            p = fmaf(row[lane * 8 + q], cr[lane * 8 + q], p);
        for (int off = 32; off >= 1; off >>= 1) p += __shfl_xor(p, off);
        if (p > bestV || (p == bestV && ci < bestI)) { bestV = p; bestI = ci; }
    }
    if (lane == 0) { wbv[wave] = bestV; wbi[wave] = bestI; }
    __syncthreads();
    if (tid == 0) {
        float bv = wbv[0]; int bi = wbi[0];
        for (int k = 1; k < 4; ++k)
            if (wbv[k] > bv || (wbv[k] == bv && wbi[k] < bi)) { bv = wbv[k]; bi = wbi[k]; }
        s_best = bi;
        out_usage[layer * KC + bi] = 1.0f;
    }
    __syncthreads();
    const int bi = s_best;

    const float* cr = CB + (size_t)bi * DD;
    const float rn0 = row[tid]       - cr[tid];
    const float rn1 = row[tid + 256] - cr[tid + 256];
    float* sp = stack + ((size_t)b * NL + layer) * DD;   // base odd-aligned -> scalar
    sp[tid]       = rn0;
    sp[tid + 256] = rn1;
    residb[(size_t)b * DD + tid]       = f2bf(rn0);
    residb[(size_t)b * DD + tid + 256] = f2bf(rn1);
    if (layer == NL - 1) {
        out_q[(size_t)b * DD + tid]       = X[(size_t)b * DD + tid]       - rn0;
        out_q[(size_t)b * DD + tid + 256] = X[(size_t)b * DD + tid + 256] - rn1;
    }
    red[tid] = rn0 * rn0 + rn1 * rn1;
    __syncthreads();
    for (int st = 128; st > 0; st >>= 1) {
        if (tid < st) red[tid] += red[tid + st];
        __syncthreads();
    }
    if (tid == 0) pl[(size_t)layer * NB + b] = red[0];
}

__global__ __launch_bounds__(256)
void k_cbsq(const float* __restrict__ cb, double* __restrict__ cq)
{
    __shared__ double red[256];
    const size_t n = (size_t)NL * KC * DD;
    double s = 0.0;
    for (size_t i = (size_t)blockIdx.x * blockDim.x + threadIdx.x; i < n;
         i += (size_t)gridDim.x * blockDim.x) {
        const float v = cb[i];
        s += (double)v * (double)v;
    }
    red[threadIdx.x] = s;
    __syncthreads();
    for (int st = 128; st > 0; st >>= 1) {
        if (threadIdx.x < st) red[threadIdx.x] += red[threadIdx.x + st];
        __syncthreads();
    }
    if (threadIdx.x == 0) cq[blockIdx.x] = red[0];
}

__global__ __launch_bounds__(256)
void k_finalize(const float* __restrict__ pl, const double* __restrict__ cq,
                int ncq, float* __restrict__ out_loss)
{
    __shared__ double red[256];
    const int tid = threadIdx.x;
    double s = 0.0;
    for (int i = tid; i < NL * NB; i += 256) s += (double)pl[i];
    double s2 = 0.0;
    for (int i = tid; i < ncq; i += 256) s2 += cq[i];
    red[tid] = s / ((double)NB * DD) + 0.01 * (s2 / ((double)NL * KC));
    __syncthreads();
    for (int st = 128; st > 0; st >>= 1) {
        if (tid < st) red[tid] += red[tid + st];
        __syncthreads();
    }
    if (tid == 0) out_loss[0] = (float)(red[0] / (double)DD);
}

extern "C" void kernel_launch(void* const* d_in, const int* in_sizes, int n_in,
                              void* d_out, int out_size, void* d_ws, size_t ws_size,
                              hipStream_t stream)
{
    (void)in_sizes; (void)n_in; (void)out_size;
    const float* x  = (const float*)d_in[0];
    // d_in[1] = temperature: positive scale, argmax-invariant, soft path cancels -> unused
    const float* cb = (const float*)d_in[2];

    float* out       = (float*)d_out;
    float* out_q     = out;                                   // [NB, DD]
    float* out_loss  = out + (size_t)NB * DD;                 // [1]
    float* out_stack = out_loss + 1;                          // [NB, NL, DD] (fp32 residual chain)
    float* out_usage = out_stack + (size_t)NB * NL * DD;      // [NL, KC]

    char* ws = (char*)d_ws;
    Top2*  part   = (Top2*)ws;                                // 4 MB
    u16*   residb = (u16*)(ws + ((size_t)4 << 20));           // 8 MB bf16 residual mirror

    const bool bigws = ws_size >= ((size_t)30 << 20);

    hipMemsetAsync(out_usage, 0, (size_t)NL * KC * sizeof(float), stream);
    k_cvt_bf16<<<(NB * DD / 4 + 255) / 256, 256, 0, stream>>>(x, residb, NB * DD / 4);

    if (bigws) {
        // cbb4: all-layer bf16 codebooks (16 MB) + fused cbsq
        u16*    cbb4 = (u16*)(ws + ((size_t)12 << 20));       // 16 MB
        float*  pl   = (float*)(ws + ((size_t)28 << 20));     // 128 KB
        double* cq   = (double*)(ws + ((size_t)28 << 20) + 131072 + 256); // 8192 doubles
        k_cvt_cbsq<<<NL * KC * DD / 4 / 256, 256, 0, stream>>>(cb, cbb4, cq);
        for (int l = 0; l < NL; ++l) {
            const float* cbl = cb + (size_t)l * KC * DD;
            k_simtop2<<<512, 1024, 0, stream>>>(residb, cbb4 + (size_t)l * KC * DD, part);
            const float* prevBase = (l == 0) ? x : (out_stack + (size_t)(l - 1) * DD);
            const size_t prevStride = (l == 0) ? (size_t)DD : (size_t)NL * DD;
            k_refine<<<NB, 256, 0, stream>>>(part, cbl, prevBase, prevStride, x, out_q,
                                             out_stack, residb, out_usage, pl, l);
        }
        k_finalize<<<1, 256, 0, stream>>>(pl, cq, 8192, out_loss);
    } else {
        u16*    cbb = (u16*)(ws + ((size_t)12 << 20));        // 4 MB per-layer
        float*  pl  = (float*)(ws + ((size_t)16 << 20));
        double* cq  = (double*)(ws + ((size_t)16 << 20) + 131072 + 256);
        k_cbsq<<<1024, 256, 0, stream>>>(cb, cq);
        for (int l = 0; l < NL; ++l) {
            const float* cbl = cb + (size_t)l * KC * DD;
            k_cvt_bf16<<<(KC * DD / 4 + 255) / 256, 256, 0, stream>>>(cbl, cbb, KC * DD / 4);
            k_simtop2<<<512, 1024, 0, stream>>>(residb, cbb, part);
            const float* prevBase = (l == 0) ? x : (out_stack + (size_t)(l - 1) * DD);
            const size_t prevStride = (l == 0) ? (size_t)DD : (size_t)NL * DD;
            k_refine<<<NB, 256, 0, stream>>>(part, cbl, prevBase, prevStride, x, out_q,
                                             out_stack, residb, out_usage, pl, l);
        }
        k_finalize<<<1, 256, 0, stream>>>(pl, cq, 1024, out_loss);
    }
}

// Round 11
// 314.965 us; speedup vs baseline: 1.4774x; 1.2270x over previous
//
#include <hip/hip_runtime.h>
#include <math.h>

#define NB 8192     // batch rows
#define DD 512      // hidden dim
#define KC 4096     // codebook size
#define NL 4        // layers

#define NTB 32      // part[] column tiles (128 codes each)
#define MARGIN 4.0f // bf16-dot candidate margin (>> 2*max bf16 dot error ~0.3)

#define GBM 256
#define GBN 256

typedef __bf16 bf16x8 __attribute__((ext_vector_type(8)));
typedef float  f32x4  __attribute__((ext_vector_type(4)));
typedef unsigned short u16;
typedef unsigned int   u32;
typedef unsigned long long u64;

struct Top2 { float v1; int i1; float v2; int i2; };

__device__ __forceinline__ u16 f2bf(float f) {   // RNE fp32 -> bf16
    unsigned u = __float_as_uint(f);
    return (u16)((u + 0x7fffu + ((u >> 16) & 1u)) >> 16);
}

__device__ __forceinline__ u32 umaxu(u32 a, u32 b) { return a > b ? a : b; }
__device__ __forceinline__ u32 uminu(u32 a, u32 b) { return a < b ? a : b; }

// monotonic fp32 -> u32 (order-preserving, incl. negatives)
__device__ __forceinline__ u32 packmono(float f) {
    u32 u = __float_as_uint(f);
    return u ^ (((u32)((int)u >> 31)) | 0x80000000u);
}
__device__ __forceinline__ float unpackv(u32 p) {
    u32 q = p & 0xFFFFFF80u;
    u32 u = (q & 0x80000000u) ? (q ^ 0x80000000u) : ~q;
    return __uint_as_float(u);
}

// fp32 -> bf16 bulk convert (n4 = count/4)
__global__ __launch_bounds__(256)
void k_cvt_bf16(const float* __restrict__ src, u16* __restrict__ dst, int n4)
{
    const int i = blockIdx.x * 256 + threadIdx.x;
    if (i < n4) {
        const float4 f = ((const float4*)src)[i];
        uint2 p;
        p.x = (unsigned)f2bf(f.x) | ((unsigned)f2bf(f.y) << 16);
        p.y = (unsigned)f2bf(f.z) | ((unsigned)f2bf(f.w) << 16);
        ((uint2*)dst)[i] = p;
    }
}

// Fused: convert ALL layers' codebooks fp32->bf16 AND accumulate sum(cb^2)
// partials. grid 8192 x 256, one float4 per thread (n4 = NL*KC*DD/4 exactly).
__global__ __launch_bounds__(256)
void k_cvt_cbsq(const float* __restrict__ src, u16* __restrict__ dst,
                double* __restrict__ cq)
{
    __shared__ double red[256];
    const int i = blockIdx.x * 256 + threadIdx.x;
    const float4 f = ((const float4*)src)[i];
    uint2 p;
    p.x = (unsigned)f2bf(f.x) | ((unsigned)f2bf(f.y) << 16);
    p.y = (unsigned)f2bf(f.z) | ((unsigned)f2bf(f.w) << 16);
    ((uint2*)dst)[i] = p;
    red[threadIdx.x] = (double)f.x * f.x + (double)f.y * f.y
                     + (double)f.z * f.z + (double)f.w * f.w;
    __syncthreads();
    for (int st = 128; st > 0; st >>= 1) {
        if (threadIdx.x < st) red[threadIdx.x] += red[threadIdx.x + st];
        __syncthreads();
    }
    if (threadIdx.x == 0) cq[blockIdx.x] = red[0];
}

// bf16 MFMA GEMM sim = Rb [NB x DD] @ Cb^T [KC x DD], 256x256 tile, BK=32.
// Exact R8 structure (proven 53us): register-staged 2 tiles ahead, single
// s_barrier/tile, both-side XOR swizzle, branchless packed-u32 top-2 epilogue.
__global__ __launch_bounds__(512, 2)
void k_simtop2(const u16* __restrict__ Rb, const u16* __restrict__ Cb,
               Top2* __restrict__ part /* [NB][NTB] */)
{
    __shared__ __align__(16) u16 As[2][8192];   // [buf][256 rows x 32 k] = 32 KB
    __shared__ __align__(16) u16 Bs[2][8192];   // 32 KB

    const int tid  = threadIdx.x;
    const int lane = tid & 63;
    const int w    = tid >> 6;        // 0..7
    const int wm   = w >> 2;          // 0..1  (row half)
    const int wn   = w & 3;           // 0..3  (col quarter)

    // XCD chunking: 512 blocks -> 8 chunks of 8x8 tiles (A 2MB + B 2MB ~ L2)
    const int bid = blockIdx.x;
    const int xcd = bid & 7;
    const int idx = bid >> 3;                           // 0..63
    const int row_pan  = (xcd >> 1) * 8 + (idx >> 3);   // 0..31
    const int col_tile = (xcd & 1) * 8 + (idx & 7);     // 0..15
    const int rb0 = row_pan * GBM;
    const int cb0 = col_tile * GBN;

    // staging: thread covers row r = tid>>1, k-chunk pair {2h, 2h+1}, h = tid&1.
    // global chunk c stored at LDS chunk c ^ f(r), f(r) = (r&3)^((r>>2)&3).
    const int rowA = tid >> 1;
    const int h    = tid & 1;
    const int fr   = (rowA & 3) ^ ((rowA >> 2) & 3);
    const char* gAb = (const char*)Rb + (size_t)(rb0 + rowA) * 1024 + h * 32;
    const char* gBb = (const char*)Cb + (size_t)(cb0 + rowA) * 1024 + h * 32;
    const int wpos0 = rowA * 64 + (((2 * h)     ^ fr) << 4);
    const int wpos1 = rowA * 64 + (((2 * h + 1) ^ fr) << 4);

    // fragment reads: row = wsub + m*16 + la, chunk = ks ^ f(la)
    const int la = lane & 15, ks = lane >> 4;
    const int fla = (la & 3) ^ ((la >> 2) & 3);
    const int offA = (wm * 128 + la) * 64 + ((ks ^ fla) << 4);
    const int offB = (wn * 64  + la) * 64 + ((ks ^ fla) << 4);

    f32x4 acc[8][4];
    const f32x4 zero = {0.f, 0.f, 0.f, 0.f};
#pragma unroll
    for (int m = 0; m < 8; ++m)
#pragma unroll
        for (int n = 0; n < 4; ++n) acc[m][n] = zero;

    uint4 eA0, eA1, eB0, eB1;   // even-tile staging regs
    uint4 oA0, oA1, oB0, oB1;   // odd-tile staging regs

#define LOADT(rA0, rA1, rB0, rB1, T) do {                    \
        const char* _pa = gAb + (T) * 64;                    \
        rA0 = *(const uint4*)(_pa);                          \
        rA1 = *(const uint4*)(_pa + 16);                     \
        const char* _pb = gBb + (T) * 64;                    \
        rB0 = *(const uint4*)(_pb);                          \
        rB1 = *(const uint4*)(_pb + 16);                     \
    } while (0)

#define ITER(T, rA0, rA1, rB0, rB1, P) do {                               \
        *(uint4*)((char*)&As[P][0] + wpos0) = rA0;                        \
        *(uint4*)((char*)&As[P][0] + wpos1) = rA1;                        \
        *(uint4*)((char*)&Bs[P][0] + wpos0) = rB0;                        \
        *(uint4*)((char*)&Bs[P][0] + wpos1) = rB1;                        \
        if ((T) + 2 < 16) LOADT(rA0, rA1, rB0, rB1, (T) + 2);             \
        asm volatile("s_waitcnt lgkmcnt(0)" ::: "memory");                \
        __builtin_amdgcn_s_barrier();                                     \
        const char* _rA = (const char*)&As[P][0];                         \
        const char* _rB = (const char*)&Bs[P][0];                         \
        bf16x8 av[8], bv[4];                                              \
        _Pragma("unroll")                                                 \
        for (int m = 0; m < 8; ++m) av[m] = *(const bf16x8*)(_rA + offA + m * 1024); \
        _Pragma("unroll")                                                 \
        for (int n = 0; n < 4; ++n) bv[n] = *(const bf16x8*)(_rB + offB + n * 1024); \
        _Pragma("unroll")                                                 \
        for (int m = 0; m < 8; ++m)                                       \
            _Pragma("unroll")                                             \
            for (int n = 0; n < 4; ++n)                                   \
                acc[m][n] = __builtin_amdgcn_mfma_f32_16x16x32_bf16(av[m], bv[n], acc[m][n], 0, 0, 0); \
    } while (0)

    LOADT(eA0, eA1, eB0, eB1, 0);
    LOADT(oA0, oA1, oB0, oB1, 1);

#pragma unroll 1
    for (int tt = 0; tt < 16; tt += 2) {
        ITER(tt,     eA0, eA1, eB0, eB1, 0);
        ITER(tt + 1, oA0, oA1, oB0, oB1, 1);
    }
#undef ITER
#undef LOADT

    __syncthreads();                           // LDS free; reuse As for merge
    uint2 (*mrg)[4] = (uint2 (*)[4])&As[0][0]; // [256 rows][4 wave-cols] = 8 KB

    // ---- branchless packed top-2 epilogue ----
    const int rgrp = lane >> 4;
    const int cidx = lane & 15;
    u32 inv[4];
#pragma unroll
    for (int n = 0; n < 4; ++n)
        inv[n] = (u32)(127 - ((wn & 1) * 64 + n * 16 + cidx));

#pragma unroll
    for (int m = 0; m < 8; ++m) {
#pragma unroll
        for (int j = 0; j < 4; ++j) {
            const u32 p0 = (packmono(acc[m][0][j]) & 0xFFFFFF80u) | inv[0];
            const u32 p1 = (packmono(acc[m][1][j]) & 0xFFFFFF80u) | inv[1];
            const u32 p2 = (packmono(acc[m][2][j]) & 0xFFFFFF80u) | inv[2];
            const u32 p3 = (packmono(acc[m][3][j]) & 0xFFFFFF80u) | inv[3];
            const u32 s1 = umaxu(p0, p1), t1 = uminu(p0, p1);
            const u32 s2 = umaxu(p2, p3), t2 = uminu(p2, p3);
            u32 hi = umaxu(s1, s2);
            u32 lo = umaxu(uminu(s1, s2), umaxu(t1, t2));
#pragma unroll
            for (int off = 1; off < 16; off <<= 1) {
                const u32 oh = (u32)__shfl_xor((int)hi, off);
                const u32 ol = (u32)__shfl_xor((int)lo, off);
                const u32 nh = umaxu(hi, oh);
                lo = umaxu(uminu(hi, oh), umaxu(lo, ol));
                hi = nh;
            }
            if (cidx == 0)
                mrg[wm * 128 + m * 16 + rgrp * 4 + j][wn] = make_uint2(hi, lo);
        }
    }
    __syncthreads();
    if (tid < 256) {   // merge wn pairs -> top-2 per 128-code half (same part format)
#pragma unroll
        for (int tau = 0; tau < 2; ++tau) {
            const uint2 a = mrg[tid][tau * 2], b = mrg[tid][tau * 2 + 1];
            const u32 hi = umaxu(a.x, b.x);
            const u32 lo = umaxu(uminu(a.x, b.x), umaxu(a.y, b.y));
            Top2 p;
            p.v1 = unpackv(hi); p.i1 = cb0 + tau * 128 + 127 - (int)(hi & 127u);
            p.v2 = unpackv(lo); p.i2 = cb0 + tau * 128 + 127 - (int)(lo & 127u);
            part[(size_t)(rb0 + tid) * NTB + col_tile * 2 + tau] = p;
        }
    }
}

// R11 refine: ONE WAVE PER ROW, fully register-resident, zero __syncthreads.
// Exact fp32 re-dot of candidates within MARGIN of the bf16 max (same selection
// semantics as before: threshold, lowest-index tie-break), residual update
// (fp32 chain via out_stack scalar + bf16 mirror vec), per-row loss partial,
// usage; layer NL-1 also writes quantized = x - r. grid 2048 x 256 (4 waves).
__global__ __launch_bounds__(256)
void k_refine(const Top2* __restrict__ part, const float* __restrict__ CB,
              const float* __restrict__ prevBase, size_t prevStride,
              const float* __restrict__ X, float* __restrict__ out_q,
              float* __restrict__ stack, u16* __restrict__ residb,
              float* __restrict__ out_usage, float* __restrict__ pl,
              int layer)
{
    const int lane = threadIdx.x & 63;
    const int b    = blockIdx.x * 4 + (threadIdx.x >> 6);   // row

    // row residual: lane holds prev[lane*8 .. lane*8+7] (scalar loads: base may
    // be odd-aligned when reading out_stack)
    const float* pr = prevBase + (size_t)b * prevStride + lane * 8;
    float r[8];
#pragma unroll
    for (int q = 0; q < 8; ++q) r[q] = pr[q];

    // candidates: lane c holds candidate c (tile c>>1, parity c&1)
    const uint4 pp = ((const uint4*)(part + (size_t)b * NTB))[lane >> 1];
    const float cv = (lane & 1) ? __uint_as_float(pp.z) : __uint_as_float(pp.x);
    const int   ci = (lane & 1) ? (int)pp.w : (int)pp.y;

    // threshold = max(cv) - MARGIN (wave reduce)
    float mx = cv;
#pragma unroll
    for (int off = 1; off < 64; off <<= 1) mx = fmaxf(mx, __shfl_xor(mx, off));
    const float thr = mx - MARGIN;

    // survivor loop: whole wave computes one exact dot per surviving candidate
    u64 mask = __ballot(cv >= thr);
    float bestV = -INFINITY;
    int   bestI = 0x7fffffff;
    while (mask) {
        const int c = __ffsll(mask) - 1;
        mask &= mask - 1;
        const int cidx = __shfl(ci, c);
        const float* cr = CB + (size_t)cidx * DD + lane * 8;
        float p = 0.f;
#pragma unroll
        for (int q = 0; q < 8; ++q) p = fmaf(r[q], cr[q], p);
#pragma unroll
        for (int off = 32; off >= 1; off >>= 1) p += __shfl_xor(p, off);
        // p uniform across lanes -> best update uniform
        if (p > bestV || (p == bestV && cidx < bestI)) { bestV = p; bestI = cidx; }
    }
    if (lane == 0) out_usage[layer * KC + bestI] = 1.0f;

    // residual update
    const float* cb = CB + (size_t)bestI * DD + lane * 8;
    float rn[8];
    float ss = 0.f;
#pragma unroll
    for (int q = 0; q < 8; ++q) { rn[q] = r[q] - cb[q]; ss = fmaf(rn[q], rn[q], ss); }

    float* sp = stack + ((size_t)b * NL + layer) * DD + lane * 8;  // odd-aligned -> scalar
#pragma unroll
    for (int q = 0; q < 8; ++q) sp[q] = rn[q];

    uint2 rb2[2];
    rb2[0].x = (u32)f2bf(rn[0]) | ((u32)f2bf(rn[1]) << 16);
    rb2[0].y = (u32)f2bf(rn[2]) | ((u32)f2bf(rn[3]) << 16);
    rb2[1].x = (u32)f2bf(rn[4]) | ((u32)f2bf(rn[5]) << 16);
    rb2[1].y = (u32)f2bf(rn[6]) | ((u32)f2bf(rn[7]) << 16);
    *(uint4*)(residb + (size_t)b * DD + lane * 8) =
        make_uint4(rb2[0].x, rb2[0].y, rb2[1].x, rb2[1].y);

    if (layer == NL - 1) {
        const float* xr = X + (size_t)b * DD + lane * 8;
        float4 q0, q1;
        q0.x = xr[0] - rn[0]; q0.y = xr[1] - rn[1];
        q0.z = xr[2] - rn[2]; q0.w = xr[3] - rn[3];
        q1.x = xr[4] - rn[4]; q1.y = xr[5] - rn[5];
        q1.z = xr[6] - rn[6]; q1.w = xr[7] - rn[7];
        float4* qp = (float4*)(out_q + (size_t)b * DD + lane * 8);
        qp[0] = q0; qp[1] = q1;
    }

    // loss partial (wave reduce)
#pragma unroll
    for (int off = 32; off >= 1; off >>= 1) ss += __shfl_xor(ss, off);
    if (lane == 0) pl[(size_t)layer * NB + b] = ss;
}

__global__ __launch_bounds__(256)
void k_cbsq(const float* __restrict__ cb, double* __restrict__ cq)
{
    __shared__ double red[256];
    const size_t n = (size_t)NL * KC * DD;
    double s = 0.0;
    for (size_t i = (size_t)blockIdx.x * blockDim.x + threadIdx.x; i < n;
         i += (size_t)gridDim.x * blockDim.x) {
        const float v = cb[i];
        s += (double)v * (double)v;
    }
    red[threadIdx.x] = s;
    __syncthreads();
    for (int st = 128; st > 0; st >>= 1) {
        if (threadIdx.x < st) red[threadIdx.x] += red[threadIdx.x + st];
        __syncthreads();
    }
    if (threadIdx.x == 0) cq[blockIdx.x] = red[0];
}

__global__ __launch_bounds__(256)
void k_finalize(const float* __restrict__ pl, const double* __restrict__ cq,
                int ncq, float* __restrict__ out_loss)
{
    __shared__ double red[256];
    const int tid = threadIdx.x;
    double s = 0.0;
    for (int i = tid; i < NL * NB; i += 256) s += (double)pl[i];
    double s2 = 0.0;
    for (int i = tid; i < ncq; i += 256) s2 += cq[i];
    red[tid] = s / ((double)NB * DD) + 0.01 * (s2 / ((double)NL * KC));
    __syncthreads();
    for (int st = 128; st > 0; st >>= 1) {
        if (tid < st) red[tid] += red[tid + st];
        __syncthreads();
    }
    if (tid == 0) out_loss[0] = (float)(red[0] / (double)DD);
}

extern "C" void kernel_launch(void* const* d_in, const int* in_sizes, int n_in,
                              void* d_out, int out_size, void* d_ws, size_t ws_size,
                              hipStream_t stream)
{
    (void)in_sizes; (void)n_in; (void)out_size;
    const float* x  = (const float*)d_in[0];
    // d_in[1] = temperature: positive scale, argmax-invariant, soft path cancels -> unused
    const float* cb = (const float*)d_in[2];

    float* out       = (float*)d_out;
    float* out_q     = out;                                   // [NB, DD]
    float* out_loss  = out + (size_t)NB * DD;                 // [1]
    float* out_stack = out_loss + 1;                          // [NB, NL, DD] (fp32 residual chain)
    float* out_usage = out_stack + (size_t)NB * NL * DD;      // [NL, KC]

    char* ws = (char*)d_ws;
    Top2*  part   = (Top2*)ws;                                // 4 MB
    u16*   residb = (u16*)(ws + ((size_t)4 << 20));           // 8 MB bf16 residual mirror

    const bool bigws = ws_size >= ((size_t)30 << 20);

    hipMemsetAsync(out_usage, 0, (size_t)NL * KC * sizeof(float), stream);
    k_cvt_bf16<<<(NB * DD / 4 + 255) / 256, 256, 0, stream>>>(x, residb, NB * DD / 4);

    if (bigws) {
        u16*    cbb4 = (u16*)(ws + ((size_t)12 << 20));       // 16 MB all-layer bf16
        float*  pl   = (float*)(ws + ((size_t)28 << 20));     // 128 KB
        double* cq   = (double*)(ws + ((size_t)28 << 20) + 131072 + 256); // 8192 doubles
        k_cvt_cbsq<<<NL * KC * DD / 4 / 256, 256, 0, stream>>>(cb, cbb4, cq);
        for (int l = 0; l < NL; ++l) {
            const float* cbl = cb + (size_t)l * KC * DD;
            k_simtop2<<<512, 512, 0, stream>>>(residb, cbb4 + (size_t)l * KC * DD, part);
            const float* prevBase = (l == 0) ? x : (out_stack + (size_t)(l - 1) * DD);
            const size_t prevStride = (l == 0) ? (size_t)DD : (size_t)NL * DD;
            k_refine<<<NB / 4, 256, 0, stream>>>(part, cbl, prevBase, prevStride, x, out_q,
                                                 out_stack, residb, out_usage, pl, l);
        }
        k_finalize<<<1, 256, 0, stream>>>(pl, cq, 8192, out_loss);
    } else {
        u16*    cbb = (u16*)(ws + ((size_t)12 << 20));        // 4 MB per-layer
        float*  pl  = (float*)(ws + ((size_t)16 << 20));
        double* cq  = (double*)(ws + ((size_t)16 << 20) + 131072 + 256);
        k_cbsq<<<1024, 256, 0, stream>>>(cb, cq);
        for (int l = 0; l < NL; ++l) {
            const float* cbl = cb + (size_t)l * KC * DD;
            k_cvt_bf16<<<(KC * DD / 4 + 255) / 256, 256, 0, stream>>>(cbl, cbb, KC * DD / 4);
            k_simtop2<<<512, 512, 0, stream>>>(residb, cbb, part);
            const float* prevBase = (l == 0) ? x : (out_stack + (size_t)(l - 1) * DD);
            const size_t prevStride = (l == 0) ? (size_t)DD : (size_t)NL * DD;
            k_refine<<<NB / 4, 256, 0, stream>>>(part, cbl, prevBase, prevStride, x, out_q,
                                                 out_stack, residb, out_usage, pl, l);
        }
        k_finalize<<<1, 256, 0, stream>>>(pl, cq, 1024, out_loss);
    }
}

// Round 12
// 262.709 us; speedup vs baseline: 1.7713x; 1.1989x over previous
//
#include <hip/hip_runtime.h>
#include <math.h>

#define NB 8192     // batch rows
#define DD 512      // hidden dim
#define KC 4096     // codebook size
#define NL 4        // layers

#define NTB 32        // part[] column tiles (128 codes each)
#define MARGIN_I 2048.0f // refine margin, int-sim units (256 x true; >10 sigma of i8 noise)
#define QS 16.0f      // i8 quantization scale

#define GBM 256
#define GBN 256

typedef int    i32x4 __attribute__((ext_vector_type(4)));
typedef unsigned short u16;
typedef unsigned int   u32;
typedef unsigned long long u64;

struct Top2 { float v1; int i1; float v2; int i2; };

__device__ __forceinline__ u32 umaxu(u32 a, u32 b) { return a > b ? a : b; }
__device__ __forceinline__ u32 uminu(u32 a, u32 b) { return a < b ? a : b; }

__device__ __forceinline__ u32 q8(float f) {   // fp32 -> signed i8 (byte), scale QS
    int v = (int)rintf(f * QS);
    v = v < -127 ? -127 : (v > 127 ? 127 : v);
    return (u32)(v & 0xFF);
}

// fp32 -> i8 bulk convert: thread i handles 8 elems (n8 = count/8)
__global__ __launch_bounds__(256)
void k_cvt_i8(const float* __restrict__ src, u64* __restrict__ dst, int n8)
{
    const int i = blockIdx.x * 256 + threadIdx.x;
    if (i < n8) {
        const float4 a = ((const float4*)src)[i * 2];
        const float4 b = ((const float4*)src)[i * 2 + 1];
        u64 p = (u64)(q8(a.x) | (q8(a.y) << 8) | (q8(a.z) << 16) | (q8(a.w) << 24))
              | ((u64)(q8(b.x) | (q8(b.y) << 8) | (q8(b.z) << 16) | (q8(b.w) << 24)) << 32);
        dst[i] = p;
    }
}

// Fused: convert ALL layers' codebooks fp32->i8 AND accumulate sum(cb^2)
// partials. grid 4096 x 256, 8 elems/thread (exact: NL*KC*DD/8/256 = 4096).
__global__ __launch_bounds__(256)
void k_cvt_cbsq_i8(const float* __restrict__ src, u64* __restrict__ dst,
                   double* __restrict__ cq)
{
    __shared__ double red[256];
    const int i = blockIdx.x * 256 + threadIdx.x;
    const float4 a = ((const float4*)src)[i * 2];
    const float4 b = ((const float4*)src)[i * 2 + 1];
    u64 p = (u64)(q8(a.x) | (q8(a.y) << 8) | (q8(a.z) << 16) | (q8(a.w) << 24))
          | ((u64)(q8(b.x) | (q8(b.y) << 8) | (q8(b.z) << 16) | (q8(b.w) << 24)) << 32);
    dst[i] = p;
    red[threadIdx.x] = (double)a.x * a.x + (double)a.y * a.y + (double)a.z * a.z
                     + (double)a.w * a.w + (double)b.x * b.x + (double)b.y * b.y
                     + (double)b.z * b.z + (double)b.w * b.w;
    __syncthreads();
    for (int st = 128; st > 0; st >>= 1) {
        if (threadIdx.x < st) red[threadIdx.x] += red[threadIdx.x + st];
        __syncthreads();
    }
    if (threadIdx.x == 0) cq[blockIdx.x] = red[0];
}

// i8 MFMA GEMM sim_int = Ri [NB x DD] @ Ci^T [KC x DD] (x256 scale), 256x256
// tile, BK=64 via mfma_i32_16x16x64_i8 (2x bf16 rate, half the bytes, 8 K-steps
// instead of 16). Geometry identical to the proven R8 bf16 kernel: 64 B per row
// per K-tile, register-staged 2 tiles ahead, single s_barrier per tile,
// both-side XOR swizzle, branchless packed-u32 top-2 epilogue (int-monotonic).
__global__ __launch_bounds__(512, 2)
void k_simtop2(const char* __restrict__ Ri, const char* __restrict__ Ci,
               Top2* __restrict__ part /* [NB][NTB] */)
{
    __shared__ __align__(16) char As[2][16384];   // [buf][256 rows x 64 B] = 32 KB
    __shared__ __align__(16) char Bs[2][16384];   // 32 KB

    const int tid  = threadIdx.x;
    const int lane = tid & 63;
    const int w    = tid >> 6;        // 0..7
    const int wm   = w >> 2;          // 0..1  (row half)
    const int wn   = w & 3;           // 0..3  (col quarter)

    // XCD chunking: 512 blocks -> 8 chunks of 8x8 tiles
    const int bid = blockIdx.x;
    const int xcd = bid & 7;
    const int idx = bid >> 3;                           // 0..63
    const int row_pan  = (xcd >> 1) * 8 + (idx >> 3);   // 0..31
    const int col_tile = (xcd & 1) * 8 + (idx & 7);     // 0..15
    const int rb0 = row_pan * GBM;
    const int cb0 = col_tile * GBN;

    // staging: thread covers row r = tid>>1, 16B-chunk pair {2h, 2h+1}, h=tid&1.
    // global chunk c stored at LDS chunk c ^ f(r), f(r) = (r&3)^((r>>2)&3).
    const int rowA = tid >> 1;
    const int h    = tid & 1;
    const int fr   = (rowA & 3) ^ ((rowA >> 2) & 3);
    const char* gAb = Ri + (size_t)(rb0 + rowA) * 512 + h * 32;
    const char* gBb = Ci + (size_t)(cb0 + rowA) * 512 + h * 32;
    const int wpos0 = rowA * 64 + (((2 * h)     ^ fr) << 4);
    const int wpos1 = rowA * 64 + (((2 * h + 1) ^ fr) << 4);

    // fragment reads: row = wsub + m*16 + la, chunk = ks ^ f(la)
    const int la = lane & 15, ks = lane >> 4;
    const int fla = (la & 3) ^ ((la >> 2) & 3);
    const int offA = (wm * 128 + la) * 64 + ((ks ^ fla) << 4);
    const int offB = (wn * 64  + la) * 64 + ((ks ^ fla) << 4);

    i32x4 acc[8][4];
    const i32x4 zero = {0, 0, 0, 0};
#pragma unroll
    for (int m = 0; m < 8; ++m)
#pragma unroll
        for (int n = 0; n < 4; ++n) acc[m][n] = zero;

    uint4 eA0, eA1, eB0, eB1;   // even-tile staging regs
    uint4 oA0, oA1, oB0, oB1;   // odd-tile staging regs

#define LOADT(rA0, rA1, rB0, rB1, T) do {                    \
        const char* _pa = gAb + (T) * 64;                    \
        rA0 = *(const uint4*)(_pa);                          \
        rA1 = *(const uint4*)(_pa + 16);                     \
        const char* _pb = gBb + (T) * 64;                    \
        rB0 = *(const uint4*)(_pb);                          \
        rB1 = *(const uint4*)(_pb + 16);                     \
    } while (0)

#define ITER(T, rA0, rA1, rB0, rB1, P) do {                               \
        *(uint4*)(&As[P][0] + wpos0) = rA0;                               \
        *(uint4*)(&As[P][0] + wpos1) = rA1;                               \
        *(uint4*)(&Bs[P][0] + wpos0) = rB0;                               \
        *(uint4*)(&Bs[P][0] + wpos1) = rB1;                               \
        if ((T) + 2 < 8) LOADT(rA0, rA1, rB0, rB1, (T) + 2);              \
        asm volatile("s_waitcnt lgkmcnt(0)" ::: "memory");                \
        __builtin_amdgcn_s_barrier();                                     \
        const char* _rA = &As[P][0];                                      \
        const char* _rB = &Bs[P][0];                                      \
        i32x4 av[8], bv[4];                                               \
        _Pragma("unroll")                                                 \
        for (int m = 0; m < 8; ++m) av[m] = *(const i32x4*)(_rA + offA + m * 1024); \
        _Pragma("unroll")                                                 \
        for (int n = 0; n < 4; ++n) bv[n] = *(const i32x4*)(_rB + offB + n * 1024); \
        _Pragma("unroll")                                                 \
        for (int m = 0; m < 8; ++m)                                       \
            _Pragma("unroll")                                             \
            for (int n = 0; n < 4; ++n)                                   \
                acc[m][n] = __builtin_amdgcn_mfma_i32_16x16x64_i8(av[m], bv[n], acc[m][n], 0, 0, 0); \
    } while (0)

    LOADT(eA0, eA1, eB0, eB1, 0);
    LOADT(oA0, oA1, oB0, oB1, 1);

#pragma unroll 1
    for (int tt = 0; tt < 8; tt += 2) {
        ITER(tt,     eA0, eA1, eB0, eB1, 0);
        ITER(tt + 1, oA0, oA1, oB0, oB1, 1);
    }
#undef ITER
#undef LOADT

    __syncthreads();                           // LDS free; reuse As for merge
    uint2 (*mrg)[4] = (uint2 (*)[4])&As[0][0]; // [256 rows][4 wave-cols] = 8 KB

    // ---- branchless packed top-2 epilogue (int-monotonic keys) ----
    // C row = (lane>>4)*4 + j (batch), col = lane&15 (code).
    // key = ((sim ^ 0x80000000) & ~0x7F) | (127 - l128)
    const int rgrp = lane >> 4;
    const int cidx = lane & 15;
    u32 inv[4];
#pragma unroll
    for (int n = 0; n < 4; ++n)
        inv[n] = (u32)(127 - ((wn & 1) * 64 + n * 16 + cidx));

#pragma unroll
    for (int m = 0; m < 8; ++m) {
#pragma unroll
        for (int j = 0; j < 4; ++j) {
            const u32 p0 = ((((u32)acc[m][0][j]) ^ 0x80000000u) & 0xFFFFFF80u) | inv[0];
            const u32 p1 = ((((u32)acc[m][1][j]) ^ 0x80000000u) & 0xFFFFFF80u) | inv[1];
            const u32 p2 = ((((u32)acc[m][2][j]) ^ 0x80000000u) & 0xFFFFFF80u) | inv[2];
            const u32 p3 = ((((u32)acc[m][3][j]) ^ 0x80000000u) & 0xFFFFFF80u) | inv[3];
            const u32 s1 = umaxu(p0, p1), t1 = uminu(p0, p1);
            const u32 s2 = umaxu(p2, p3), t2 = uminu(p2, p3);
            u32 hi = umaxu(s1, s2);
            u32 lo = umaxu(uminu(s1, s2), umaxu(t1, t2));
#pragma unroll
            for (int off = 1; off < 16; off <<= 1) {
                const u32 oh = (u32)__shfl_xor((int)hi, off);
                const u32 ol = (u32)__shfl_xor((int)lo, off);
                const u32 nh = umaxu(hi, oh);
                lo = umaxu(uminu(hi, oh), umaxu(lo, ol));
                hi = nh;
            }
            if (cidx == 0)
                mrg[wm * 128 + m * 16 + rgrp * 4 + j][wn] = make_uint2(hi, lo);
        }
    }
    __syncthreads();
    if (tid < 256) {   // merge wn pairs -> top-2 per 128-code half
#pragma unroll
        for (int tau = 0; tau < 2; ++tau) {
            const uint2 a = mrg[tid][tau * 2], b = mrg[tid][tau * 2 + 1];
            const u32 hi = umaxu(a.x, b.x);
            const u32 lo = umaxu(uminu(a.x, b.x), umaxu(a.y, b.y));
            Top2 p;
            p.v1 = (float)(int)((hi & 0xFFFFFF80u) ^ 0x80000000u);
            p.i1 = cb0 + tau * 128 + 127 - (int)(hi & 127u);
            p.v2 = (float)(int)((lo & 0xFFFFFF80u) ^ 0x80000000u);
            p.i2 = cb0 + tau * 128 + 127 - (int)(lo & 127u);
            part[(size_t)(rb0 + tid) * NTB + col_tile * 2 + tau] = p;
        }
    }
}

// Refine: ONE WAVE PER ROW, register-resident, zero __syncthreads (R11 proven).
// Exact fp32 re-dot of candidates within MARGIN_I of the int-sim max, argmax
// (lowest-index tie-break), residual update (fp32 chain via out_stack + i8
// mirror for next GEMM), per-row loss partial, usage; layer NL-1 writes
// quantized = x - r. grid NB/4 x 256.
__global__ __launch_bounds__(256)
void k_refine(const Top2* __restrict__ part, const float* __restrict__ CB,
              const float* __restrict__ prevBase, size_t prevStride,
              const float* __restrict__ X, float* __restrict__ out_q,
              float* __restrict__ stack, char* __restrict__ residq,
              float* __restrict__ out_usage, float* __restrict__ pl,
              int layer)
{
    const int lane = threadIdx.x & 63;
    const int b    = blockIdx.x * 4 + (threadIdx.x >> 6);   // row

    const float* pr = prevBase + (size_t)b * prevStride + lane * 8;
    float r[8];
#pragma unroll
    for (int q = 0; q < 8; ++q) r[q] = pr[q];

    // candidates: lane c holds candidate c (tile c>>1, parity c&1)
    const uint4 pp = ((const uint4*)(part + (size_t)b * NTB))[lane >> 1];
    const float cv = (lane & 1) ? __uint_as_float(pp.z) : __uint_as_float(pp.x);
    const int   ci = (lane & 1) ? (int)pp.w : (int)pp.y;

    float mx = cv;
#pragma unroll
    for (int off = 1; off < 64; off <<= 1) mx = fmaxf(mx, __shfl_xor(mx, off));
    const float thr = mx - MARGIN_I;

    u64 mask = __ballot(cv >= thr);
    float bestV = -INFINITY;
    int   bestI = 0x7fffffff;
    while (mask) {
        const int c = __ffsll(mask) - 1;
        mask &= mask - 1;
        const int cidx = __shfl(ci, c);
        const float* cr = CB + (size_t)cidx * DD + lane * 8;
        float p = 0.f;
#pragma unroll
        for (int q = 0; q < 8; ++q) p = fmaf(r[q], cr[q], p);
#pragma unroll
        for (int off = 32; off >= 1; off >>= 1) p += __shfl_xor(p, off);
        if (p > bestV || (p == bestV && cidx < bestI)) { bestV = p; bestI = cidx; }
    }
    if (lane == 0) out_usage[layer * KC + bestI] = 1.0f;

    const float* cb = CB + (size_t)bestI * DD + lane * 8;
    float rn[8];
    float ss = 0.f;
#pragma unroll
    for (int q = 0; q < 8; ++q) { rn[q] = r[q] - cb[q]; ss = fmaf(rn[q], rn[q], ss); }

    float* sp = stack + ((size_t)b * NL + layer) * DD + lane * 8;  // odd-aligned -> scalar
#pragma unroll
    for (int q = 0; q < 8; ++q) sp[q] = rn[q];

    // i8 mirror for next layer's GEMM (8 B per lane, contiguous)
    u64 pq = (u64)(q8(rn[0]) | (q8(rn[1]) << 8) | (q8(rn[2]) << 16) | (q8(rn[3]) << 24))
           | ((u64)(q8(rn[4]) | (q8(rn[5]) << 8) | (q8(rn[6]) << 16) | (q8(rn[7]) << 24)) << 32);
    *(u64*)(residq + (size_t)b * DD + lane * 8) = pq;

    if (layer == NL - 1) {
        const float* xr = X + (size_t)b * DD + lane * 8;
        float4 q0, q1;
        q0.x = xr[0] - rn[0]; q0.y = xr[1] - rn[1];
        q0.z = xr[2] - rn[2]; q0.w = xr[3] - rn[3];
        q1.x = xr[4] - rn[4]; q1.y = xr[5] - rn[5];
        q1.z = xr[6] - rn[6]; q1.w = xr[7] - rn[7];
        float4* qp = (float4*)(out_q + (size_t)b * DD + lane * 8);
        qp[0] = q0; qp[1] = q1;
    }

#pragma unroll
    for (int off = 32; off >= 1; off >>= 1) ss += __shfl_xor(ss, off);
    if (lane == 0) pl[(size_t)layer * NB + b] = ss;
}

__global__ __launch_bounds__(256)
void k_finalize(const float* __restrict__ pl, const double* __restrict__ cq,
                int ncq, float* __restrict__ out_loss)
{
    __shared__ double red[256];
    const int tid = threadIdx.x;
    double s = 0.0;
    for (int i = tid; i < NL * NB; i += 256) s += (double)pl[i];
    double s2 = 0.0;
    for (int i = tid; i < ncq; i += 256) s2 += cq[i];
    red[tid] = s / ((double)NB * DD) + 0.01 * (s2 / ((double)NL * KC));
    __syncthreads();
    for (int st = 128; st > 0; st >>= 1) {
        if (tid < st) red[tid] += red[tid + st];
        __syncthreads();
    }
    if (tid == 0) out_loss[0] = (float)(red[0] / (double)DD);
}

extern "C" void kernel_launch(void* const* d_in, const int* in_sizes, int n_in,
                              void* d_out, int out_size, void* d_ws, size_t ws_size,
                              hipStream_t stream)
{
    (void)in_sizes; (void)n_in; (void)out_size; (void)ws_size;
    const float* x  = (const float*)d_in[0];
    // d_in[1] = temperature: positive scale, argmax-invariant, soft path cancels -> unused
    const float* cb = (const float*)d_in[2];

    float* out       = (float*)d_out;
    float* out_q     = out;                                   // [NB, DD]
    float* out_loss  = out + (size_t)NB * DD;                 // [1]
    float* out_stack = out_loss + 1;                          // [NB, NL, DD] (fp32 residual chain)
    float* out_usage = out_stack + (size_t)NB * NL * DD;      // [NL, KC]

    char* ws = (char*)d_ws;
    Top2*  part   = (Top2*)ws;                                // 4 MB
    char*  residq = ws + ((size_t)4 << 20);                   // 4 MB i8 residual mirror
    char*  cbq    = ws + ((size_t)8 << 20);                   // 8 MB i8 codebooks (all layers)
    float* pl     = (float*)(ws + ((size_t)16 << 20));        // 128 KB loss partials
    double* cq    = (double*)(ws + ((size_t)16 << 20) + 131072 + 256); // 4096 doubles

    hipMemsetAsync(out_usage, 0, (size_t)NL * KC * sizeof(float), stream);

    k_cvt_i8<<<(NB * DD / 8 + 255) / 256, 256, 0, stream>>>(x, (u64*)residq, NB * DD / 8);
    k_cvt_cbsq_i8<<<NL * KC * DD / 8 / 256, 256, 0, stream>>>(cb, (u64*)cbq, cq);

    for (int l = 0; l < NL; ++l) {
        const float* cbl = cb + (size_t)l * KC * DD;
        k_simtop2<<<512, 512, 0, stream>>>(residq, cbq + (size_t)l * KC * DD, part);
        const float* prevBase = (l == 0) ? x : (out_stack + (size_t)(l - 1) * DD);
        const size_t prevStride = (l == 0) ? (size_t)DD : (size_t)NL * DD;
        k_refine<<<NB / 4, 256, 0, stream>>>(part, cbl, prevBase, prevStride, x, out_q,
                                             out_stack, residq, out_usage, pl, l);
    }
    k_finalize<<<1, 256, 0, stream>>>(pl, cq, 4096, out_loss);
}

// Round 13
// 254.493 us; speedup vs baseline: 1.8284x; 1.0323x over previous
//
#include <hip/hip_runtime.h>
#include <math.h>

#define NB 8192     // batch rows
#define DD 512      // hidden dim
#define KC 4096     // codebook size
#define NL 4        // layers

#define NTB 32        // part[] column tiles (128 codes each)
#define MARGIN_I 2048.0f // refine margin, int-sim units (256 x true; >10 sigma of i8 noise)
#define QS 16.0f      // i8 quantization scale

#define GBM 256
#define GBN 256

typedef int    i32x4 __attribute__((ext_vector_type(4)));
typedef unsigned short u16;
typedef unsigned int   u32;
typedef unsigned long long u64;

struct Top2 { float v1; int i1; float v2; int i2; };

__device__ __forceinline__ u32 umaxu(u32 a, u32 b) { return a > b ? a : b; }
__device__ __forceinline__ u32 uminu(u32 a, u32 b) { return a < b ? a : b; }

__device__ __forceinline__ u32 q8(float f) {   // fp32 -> signed i8 (byte), scale QS
    int v = (int)rintf(f * QS);
    v = v < -127 ? -127 : (v > 127 ? 127 : v);
    return (u32)(v & 0xFF);
}

// fp32 -> i8 bulk convert: thread i handles 8 elems (n8 = count/8)
__global__ __launch_bounds__(256)
void k_cvt_i8(const float* __restrict__ src, u64* __restrict__ dst, int n8)
{
    const int i = blockIdx.x * 256 + threadIdx.x;
    if (i < n8) {
        const float4 a = ((const float4*)src)[i * 2];
        const float4 b = ((const float4*)src)[i * 2 + 1];
        u64 p = (u64)(q8(a.x) | (q8(a.y) << 8) | (q8(a.z) << 16) | (q8(a.w) << 24))
              | ((u64)(q8(b.x) | (q8(b.y) << 8) | (q8(b.z) << 16) | (q8(b.w) << 24)) << 32);
        dst[i] = p;
    }
}

// Fused: convert ALL layers' codebooks fp32->i8, accumulate sum(cb^2) partials,
// AND zero out_usage (replaces hipMemsetAsync -- rocprof showed the runtime's
// fillBufferAligned kernel costs ~49us per replay regardless of size).
// grid 4096 x 256, 8 elems/thread (exact: NL*KC*DD/8/256 = 4096).
__global__ __launch_bounds__(256)
void k_cvt_cbsq_i8(const float* __restrict__ src, u64* __restrict__ dst,
                   double* __restrict__ cq, float* __restrict__ usage)
{
    __shared__ double red[256];
    const int i = blockIdx.x * 256 + threadIdx.x;
    if (blockIdx.x < 64) {   // 64*256 threads x 4 floats = 65536 = NL*KC
        const float4 z = {0.f, 0.f, 0.f, 0.f};
        ((float4*)usage)[i] = z;
    }
    const float4 a = ((const float4*)src)[i * 2];
    const float4 b = ((const float4*)src)[i * 2 + 1];
    u64 p = (u64)(q8(a.x) | (q8(a.y) << 8) | (q8(a.z) << 16) | (q8(a.w) << 24))
          | ((u64)(q8(b.x) | (q8(b.y) << 8) | (q8(b.z) << 16) | (q8(b.w) << 24)) << 32);
    dst[i] = p;
    red[threadIdx.x] = (double)a.x * a.x + (double)a.y * a.y + (double)a.z * a.z
                     + (double)a.w * a.w + (double)b.x * b.x + (double)b.y * b.y
                     + (double)b.z * b.z + (double)b.w * b.w;
    __syncthreads();
    for (int st = 128; st > 0; st >>= 1) {
        if (threadIdx.x < st) red[threadIdx.x] += red[threadIdx.x + st];
        __syncthreads();
    }
    if (threadIdx.x == 0) cq[blockIdx.x] = red[0];
}

// i8 MFMA GEMM sim_int = Ri [NB x DD] @ Ci^T [KC x DD] (x256 scale), 256x256
// tile, BK=64 via mfma_i32_16x16x64_i8 (2x bf16 rate, half the bytes, 8 K-steps).
// Geometry identical to the proven R8 structure: register-staged 2 tiles ahead,
// single s_barrier per tile, both-side XOR swizzle, branchless packed top-2.
__global__ __launch_bounds__(512, 2)
void k_simtop2(const char* __restrict__ Ri, const char* __restrict__ Ci,
               Top2* __restrict__ part /* [NB][NTB] */)
{
    __shared__ __align__(16) char As[2][16384];   // [buf][256 rows x 64 B] = 32 KB
    __shared__ __align__(16) char Bs[2][16384];   // 32 KB

    const int tid  = threadIdx.x;
    const int lane = tid & 63;
    const int w    = tid >> 6;        // 0..7
    const int wm   = w >> 2;          // 0..1  (row half)
    const int wn   = w & 3;           // 0..3  (col quarter)

    // XCD chunking: 512 blocks -> 8 chunks of 8x8 tiles
    const int bid = blockIdx.x;
    const int xcd = bid & 7;
    const int idx = bid >> 3;                           // 0..63
    const int row_pan  = (xcd >> 1) * 8 + (idx >> 3);   // 0..31
    const int col_tile = (xcd & 1) * 8 + (idx & 7);     // 0..15
    const int rb0 = row_pan * GBM;
    const int cb0 = col_tile * GBN;

    // staging: thread covers row r = tid>>1, 16B-chunk pair {2h, 2h+1}, h=tid&1.
    // global chunk c stored at LDS chunk c ^ f(r), f(r) = (r&3)^((r>>2)&3).
    const int rowA = tid >> 1;
    const int h    = tid & 1;
    const int fr   = (rowA & 3) ^ ((rowA >> 2) & 3);
    const char* gAb = Ri + (size_t)(rb0 + rowA) * 512 + h * 32;
    const char* gBb = Ci + (size_t)(cb0 + rowA) * 512 + h * 32;
    const int wpos0 = rowA * 64 + (((2 * h)     ^ fr) << 4);
    const int wpos1 = rowA * 64 + (((2 * h + 1) ^ fr) << 4);

    // fragment reads: row = wsub + m*16 + la, chunk = ks ^ f(la)
    const int la = lane & 15, ks = lane >> 4;
    const int fla = (la & 3) ^ ((la >> 2) & 3);
    const int offA = (wm * 128 + la) * 64 + ((ks ^ fla) << 4);
    const int offB = (wn * 64  + la) * 64 + ((ks ^ fla) << 4);

    i32x4 acc[8][4];
    const i32x4 zero = {0, 0, 0, 0};
#pragma unroll
    for (int m = 0; m < 8; ++m)
#pragma unroll
        for (int n = 0; n < 4; ++n) acc[m][n] = zero;

    uint4 eA0, eA1, eB0, eB1;   // even-tile staging regs
    uint4 oA0, oA1, oB0, oB1;   // odd-tile staging regs

#define LOADT(rA0, rA1, rB0, rB1, T) do {                    \
        const char* _pa = gAb + (T) * 64;                    \
        rA0 = *(const uint4*)(_pa);                          \
        rA1 = *(const uint4*)(_pa + 16);                     \
        const char* _pb = gBb + (T) * 64;                    \
        rB0 = *(const uint4*)(_pb);                          \
        rB1 = *(const uint4*)(_pb + 16);                     \
    } while (0)

#define ITER(T, rA0, rA1, rB0, rB1, P) do {                               \
        *(uint4*)(&As[P][0] + wpos0) = rA0;                               \
        *(uint4*)(&As[P][0] + wpos1) = rA1;                               \
        *(uint4*)(&Bs[P][0] + wpos0) = rB0;                               \
        *(uint4*)(&Bs[P][0] + wpos1) = rB1;                               \
        if ((T) + 2 < 8) LOADT(rA0, rA1, rB0, rB1, (T) + 2);              \
        asm volatile("s_waitcnt lgkmcnt(0)" ::: "memory");                \
        __builtin_amdgcn_s_barrier();                                     \
        const char* _rA = &As[P][0];                                      \
        const char* _rB = &Bs[P][0];                                      \
        i32x4 av[8], bv[4];                                               \
        _Pragma("unroll")                                                 \
        for (int m = 0; m < 8; ++m) av[m] = *(const i32x4*)(_rA + offA + m * 1024); \
        _Pragma("unroll")                                                 \
        for (int n = 0; n < 4; ++n) bv[n] = *(const i32x4*)(_rB + offB + n * 1024); \
        _Pragma("unroll")                                                 \
        for (int m = 0; m < 8; ++m)                                       \
            _Pragma("unroll")                                             \
            for (int n = 0; n < 4; ++n)                                   \
                acc[m][n] = __builtin_amdgcn_mfma_i32_16x16x64_i8(av[m], bv[n], acc[m][n], 0, 0, 0); \
    } while (0)

    LOADT(eA0, eA1, eB0, eB1, 0);
    LOADT(oA0, oA1, oB0, oB1, 1);

#pragma unroll 1
    for (int tt = 0; tt < 8; tt += 2) {
        ITER(tt,     eA0, eA1, eB0, eB1, 0);
        ITER(tt + 1, oA0, oA1, oB0, oB1, 1);
    }
#undef ITER
#undef LOADT

    __syncthreads();                           // LDS free; reuse As for merge
    uint2 (*mrg)[4] = (uint2 (*)[4])&As[0][0]; // [256 rows][4 wave-cols] = 8 KB

    // ---- branchless packed top-2 epilogue (int-monotonic keys) ----
    // key = ((sim ^ 0x80000000) & ~0x7F) | (127 - l128)
    const int rgrp = lane >> 4;
    const int cidx = lane & 15;
    u32 inv[4];
#pragma unroll
    for (int n = 0; n < 4; ++n)
        inv[n] = (u32)(127 - ((wn & 1) * 64 + n * 16 + cidx));

#pragma unroll
    for (int m = 0; m < 8; ++m) {
#pragma unroll
        for (int j = 0; j < 4; ++j) {
            const u32 p0 = ((((u32)acc[m][0][j]) ^ 0x80000000u) & 0xFFFFFF80u) | inv[0];
            const u32 p1 = ((((u32)acc[m][1][j]) ^ 0x80000000u) & 0xFFFFFF80u) | inv[1];
            const u32 p2 = ((((u32)acc[m][2][j]) ^ 0x80000000u) & 0xFFFFFF80u) | inv[2];
            const u32 p3 = ((((u32)acc[m][3][j]) ^ 0x80000000u) & 0xFFFFFF80u) | inv[3];
            const u32 s1 = umaxu(p0, p1), t1 = uminu(p0, p1);
            const u32 s2 = umaxu(p2, p3), t2 = uminu(p2, p3);
            u32 hi = umaxu(s1, s2);
            u32 lo = umaxu(uminu(s1, s2), umaxu(t1, t2));
#pragma unroll
            for (int off = 1; off < 16; off <<= 1) {
                const u32 oh = (u32)__shfl_xor((int)hi, off);
                const u32 ol = (u32)__shfl_xor((int)lo, off);
                const u32 nh = umaxu(hi, oh);
                lo = umaxu(uminu(hi, oh), umaxu(lo, ol));
                hi = nh;
            }
            if (cidx == 0)
                mrg[wm * 128 + m * 16 + rgrp * 4 + j][wn] = make_uint2(hi, lo);
        }
    }
    __syncthreads();
    if (tid < 256) {   // merge wn pairs -> top-2 per 128-code half
#pragma unroll
        for (int tau = 0; tau < 2; ++tau) {
            const uint2 a = mrg[tid][tau * 2], b = mrg[tid][tau * 2 + 1];
            const u32 hi = umaxu(a.x, b.x);
            const u32 lo = umaxu(uminu(a.x, b.x), umaxu(a.y, b.y));
            Top2 p;
            p.v1 = (float)(int)((hi & 0xFFFFFF80u) ^ 0x80000000u);
            p.i1 = cb0 + tau * 128 + 127 - (int)(hi & 127u);
            p.v2 = (float)(int)((lo & 0xFFFFFF80u) ^ 0x80000000u);
            p.i2 = cb0 + tau * 128 + 127 - (int)(lo & 127u);
            part[(size_t)(rb0 + tid) * NTB + col_tile * 2 + tau] = p;
        }
    }
}

// Refine: ONE WAVE PER ROW, register-resident, zero __syncthreads.
// Exact fp32 re-dot of candidates within MARGIN_I of the int-sim max, argmax
// (lowest-index tie-break), residual update (fp32 chain via out_stack + i8
// mirror for next GEMM), per-row loss partial, usage; layer NL-1 writes
// quantized = x - r. grid NB/4 x 256.
__global__ __launch_bounds__(256)
void k_refine(const Top2* __restrict__ part, const float* __restrict__ CB,
              const float* __restrict__ prevBase, size_t prevStride,
              const float* __restrict__ X, float* __restrict__ out_q,
              float* __restrict__ stack, char* __restrict__ residq,
              float* __restrict__ out_usage, float* __restrict__ pl,
              int layer)
{
    const int lane = threadIdx.x & 63;
    const int b    = blockIdx.x * 4 + (threadIdx.x >> 6);   // row

    const float* pr = prevBase + (size_t)b * prevStride + lane * 8;
    float r[8];
#pragma unroll
    for (int q = 0; q < 8; ++q) r[q] = pr[q];

    // candidates: lane c holds candidate c (tile c>>1, parity c&1)
    const uint4 pp = ((const uint4*)(part + (size_t)b * NTB))[lane >> 1];
    const float cv = (lane & 1) ? __uint_as_float(pp.z) : __uint_as_float(pp.x);
    const int   ci = (lane & 1) ? (int)pp.w : (int)pp.y;

    float mx = cv;
#pragma unroll
    for (int off = 1; off < 64; off <<= 1) mx = fmaxf(mx, __shfl_xor(mx, off));
    const float thr = mx - MARGIN_I;

    u64 mask = __ballot(cv >= thr);
    float bestV = -INFINITY;
    int   bestI = 0x7fffffff;
    while (mask) {
        const int c = __ffsll(mask) - 1;
        mask &= mask - 1;
        const int cidx = __shfl(ci, c);
        const float* cr = CB + (size_t)cidx * DD + lane * 8;
        float p = 0.f;
#pragma unroll
        for (int q = 0; q < 8; ++q) p = fmaf(r[q], cr[q], p);
#pragma unroll
        for (int off = 32; off >= 1; off >>= 1) p += __shfl_xor(p, off);
        if (p > bestV || (p == bestV && cidx < bestI)) { bestV = p; bestI = cidx; }
    }
    if (lane == 0) out_usage[layer * KC + bestI] = 1.0f;

    const float* cb = CB + (size_t)bestI * DD + lane * 8;
    float rn[8];
    float ss = 0.f;
#pragma unroll
    for (int q = 0; q < 8; ++q) { rn[q] = r[q] - cb[q]; ss = fmaf(rn[q], rn[q], ss); }

    float* sp = stack + ((size_t)b * NL + layer) * DD + lane * 8;  // odd-aligned -> scalar
#pragma unroll
    for (int q = 0; q < 8; ++q) sp[q] = rn[q];

    // i8 mirror for next layer's GEMM (8 B per lane, contiguous)
    u64 pq = (u64)(q8(rn[0]) | (q8(rn[1]) << 8) | (q8(rn[2]) << 16) | (q8(rn[3]) << 24))
           | ((u64)(q8(rn[4]) | (q8(rn[5]) << 8) | (q8(rn[6]) << 16) | (q8(rn[7]) << 24)) << 32);
    *(u64*)(residq + (size_t)b * DD + lane * 8) = pq;

    if (layer == NL - 1) {
        const float* xr = X + (size_t)b * DD + lane * 8;
        float4 q0, q1;
        q0.x = xr[0] - rn[0]; q0.y = xr[1] - rn[1];
        q0.z = xr[2] - rn[2]; q0.w = xr[3] - rn[3];
        q1.x = xr[4] - rn[4]; q1.y = xr[5] - rn[5];
        q1.z = xr[6] - rn[6]; q1.w = xr[7] - rn[7];
        float4* qp = (float4*)(out_q + (size_t)b * DD + lane * 8);
        qp[0] = q0; qp[1] = q1;
    }

#pragma unroll
    for (int off = 32; off >= 1; off >>= 1) ss += __shfl_xor(ss, off);
    if (lane == 0) pl[(size_t)layer * NB + b] = ss;
}

__global__ __launch_bounds__(256)
void k_finalize(const float* __restrict__ pl, const double* __restrict__ cq,
                int ncq, float* __restrict__ out_loss)
{
    __shared__ double red[256];
    const int tid = threadIdx.x;
    double s = 0.0;
    for (int i = tid; i < NL * NB; i += 256) s += (double)pl[i];
    double s2 = 0.0;
    for (int i = tid; i < ncq; i += 256) s2 += cq[i];
    red[tid] = s / ((double)NB * DD) + 0.01 * (s2 / ((double)NL * KC));
    __syncthreads();
    for (int st = 128; st > 0; st >>= 1) {
        if (tid < st) red[tid] += red[tid + st];
        __syncthreads();
    }
    if (tid == 0) out_loss[0] = (float)(red[0] / (double)DD);
}

extern "C" void kernel_launch(void* const* d_in, const int* in_sizes, int n_in,
                              void* d_out, int out_size, void* d_ws, size_t ws_size,
                              hipStream_t stream)
{
    (void)in_sizes; (void)n_in; (void)out_size; (void)ws_size;
    const float* x  = (const float*)d_in[0];
    // d_in[1] = temperature: positive scale, argmax-invariant, soft path cancels -> unused
    const float* cb = (const float*)d_in[2];

    float* out       = (float*)d_out;
    float* out_q     = out;                                   // [NB, DD]
    float* out_loss  = out + (size_t)NB * DD;                 // [1]
    float* out_stack = out_loss + 1;                          // [NB, NL, DD] (fp32 residual chain)
    float* out_usage = out_stack + (size_t)NB * NL * DD;      // [NL, KC]

    char* ws = (char*)d_ws;
    Top2*  part   = (Top2*)ws;                                // 4 MB
    char*  residq = ws + ((size_t)4 << 20);                   // 4 MB i8 residual mirror
    char*  cbq    = ws + ((size_t)8 << 20);                   // 8 MB i8 codebooks (all layers)
    float* pl     = (float*)(ws + ((size_t)16 << 20));        // 128 KB loss partials
    double* cq    = (double*)(ws + ((size_t)16 << 20) + 131072 + 256); // 4096 doubles

    k_cvt_i8<<<(NB * DD / 8 + 255) / 256, 256, 0, stream>>>(x, (u64*)residq, NB * DD / 8);
    k_cvt_cbsq_i8<<<NL * KC * DD / 8 / 256, 256, 0, stream>>>(cb, (u64*)cbq, cq, out_usage);

    for (int l = 0; l < NL; ++l) {
        const float* cbl = cb + (size_t)l * KC * DD;
        k_simtop2<<<512, 512, 0, stream>>>(residq, cbq + (size_t)l * KC * DD, part);
        const float* prevBase = (l == 0) ? x : (out_stack + (size_t)(l - 1) * DD);
        const size_t prevStride = (l == 0) ? (size_t)DD : (size_t)NL * DD;
        k_refine<<<NB / 4, 256, 0, stream>>>(part, cbl, prevBase, prevStride, x, out_q,
                                             out_stack, residq, out_usage, pl, l);
    }
    k_finalize<<<1, 256, 0, stream>>>(pl, cq, 4096, out_loss);
}